// Round 10
// baseline (13714.661 us; speedup 1.0000x reference)
//
#include <hip/hip_runtime.h>
#include <hip/hip_bf16.h>
#include <math.h>

#define NNODES 100000
#define NFEAT 512
#define NHID 256
#define NCLS 64
#define ALPHA_C 0.1f

#define CHUNK_SHIFT 14     // col chunk = col >> 14 (2.1MB x-slab, L2-resident)
#define RBLK 128           // rows per rowblock / spmm block
#define NPB 256            // partition blocks for level-1 scatter
#define KMAX 1024          // max rowblock keys (782 for N=100k)

typedef short s16x8 __attribute__((ext_vector_type(8)));
typedef float f32x4 __attribute__((ext_vector_type(4)));

__device__ inline unsigned short f2b(float f) {
    union { float f; unsigned u; } v; v.f = f;
    unsigned r = v.u + 0x7fff + ((v.u >> 16) & 1);   // RNE
    return (unsigned short)(r >> 16);
}
__device__ inline float b2f(unsigned short b) {
    return __uint_as_float((unsigned)b << 16);
}
__device__ inline float blo(unsigned u) { return __uint_as_float(u << 16); }
__device__ inline float bhi(unsigned u) { return __uint_as_float(u & 0xffff0000u); }

// ---------------- transpose+convert: dst[C][R] bf16 <- src[R][C] fp32 ----------------
__global__ __launch_bounds__(256) void cvtT_kernel(
    const float* __restrict__ src, unsigned short* __restrict__ dst, int R, int Clog2)
{
    int idx = blockIdx.x * 256 + threadIdx.x;
    int C = 1 << Clog2;
    if (idx < R * C) {
        int r = idx >> Clog2, c = idx & (C - 1);
        dst[(size_t)c * R + r] = f2b(src[idx]);
    }
}

// ---------------- fused MFMA MLP: h = relu(feat@W1+b1)@W2 + b2 (bf16 out) ------------
#define HID_STRIDE 264   // 256 + 8 pad

__global__ __launch_bounds__(256) void mlp_mfma_kernel(
    const float* __restrict__ feat, const unsigned short* __restrict__ W1T,
    const float* __restrict__ b1, const unsigned short* __restrict__ W2T,
    const float* __restrict__ b2, unsigned short* __restrict__ h, int N)
{
    __shared__ unsigned short hid_s[64 * HID_STRIDE];
    const int tid  = threadIdx.x;
    const int w    = tid >> 6;
    const int lane = tid & 63;
    const int lr   = lane & 15;
    const int lh   = lane >> 4;
    const int m0   = blockIdx.x * 64;

    f32x4 acc[4][4];
#pragma unroll
    for (int i = 0; i < 4; ++i)
#pragma unroll
        for (int j = 0; j < 4; ++j) acc[i][j] = (f32x4)0.f;

    const float* arow[4];
#pragma unroll
    for (int mi = 0; mi < 4; ++mi) {
        int r = m0 + mi * 16 + lr;
        if (r > N - 1) r = N - 1;
        arow[mi] = feat + (size_t)r * NFEAT;
    }
    const unsigned short* brow[4];
#pragma unroll
    for (int nj = 0; nj < 4; ++nj)
        brow[nj] = W1T + (size_t)(w * 64 + nj * 16 + lr) * NFEAT;

    for (int kb = 0; kb < NFEAT; kb += 32) {
        const int k0 = kb + lh * 8;
        s16x8 afr[4], bfr[4];
#pragma unroll
        for (int mi = 0; mi < 4; ++mi) {
            float4 f0 = *reinterpret_cast<const float4*>(arow[mi] + k0);
            float4 f1 = *reinterpret_cast<const float4*>(arow[mi] + k0 + 4);
            s16x8 a;
            a[0] = f2b(f0.x); a[1] = f2b(f0.y); a[2] = f2b(f0.z); a[3] = f2b(f0.w);
            a[4] = f2b(f1.x); a[5] = f2b(f1.y); a[6] = f2b(f1.z); a[7] = f2b(f1.w);
            afr[mi] = a;
        }
#pragma unroll
        for (int nj = 0; nj < 4; ++nj)
            bfr[nj] = *reinterpret_cast<const s16x8*>(brow[nj] + k0);
#pragma unroll
        for (int mi = 0; mi < 4; ++mi)
#pragma unroll
            for (int nj = 0; nj < 4; ++nj)
                acc[mi][nj] = __builtin_amdgcn_mfma_f32_16x16x32_bf16(
                    afr[mi], bfr[nj], acc[mi][nj], 0, 0, 0);
    }

#pragma unroll
    for (int nj = 0; nj < 4; ++nj) {
        int col = w * 64 + nj * 16 + lr;
        float bias = b1[col];
#pragma unroll
        for (int mi = 0; mi < 4; ++mi)
#pragma unroll
            for (int q = 0; q < 4; ++q) {
                int row = mi * 16 + lh * 4 + q;
                hid_s[row * HID_STRIDE + col] = f2b(fmaxf(acc[mi][nj][q] + bias, 0.f));
            }
    }
    __syncthreads();

    f32x4 acc2[4];
#pragma unroll
    for (int i = 0; i < 4; ++i) acc2[i] = (f32x4)0.f;
    const int cw = w * 16;
    const unsigned short* b2row = W2T + (size_t)(cw + lr) * NHID;
    for (int ks = 0; ks < NHID; ks += 32) {
        int k0 = ks + lh * 8;
        s16x8 bfr = *reinterpret_cast<const s16x8*>(b2row + k0);
#pragma unroll
        for (int mi = 0; mi < 4; ++mi) {
            s16x8 afr = *reinterpret_cast<const s16x8*>(
                &hid_s[(mi * 16 + lr) * HID_STRIDE + k0]);
            acc2[mi] = __builtin_amdgcn_mfma_f32_16x16x32_bf16(afr, bfr, acc2[mi], 0, 0, 0);
        }
    }
    int col = cw + lr;
    float bias2 = b2[col];
#pragma unroll
    for (int mi = 0; mi < 4; ++mi)
#pragma unroll
        for (int q = 0; q < 4; ++q) {
            int row = m0 + mi * 16 + lh * 4 + q;
            if (row < N) h[(size_t)row * NCLS + col] = f2b(acc2[mi][q] + bias2);
        }
}

// ------------- level-1 scatter: key = rowblock (row>>7) -------------
// pass 1: per partition-block histogram; cnt_t[blk][k] (blk-major, coalesced)
__global__ __launch_bounds__(256) void countP1_kernel(
    const int* __restrict__ erow, int* __restrict__ cnt_t, int E, int CE, int K)
{
    __shared__ int c[KMAX];
    const int blk = blockIdx.x, t = threadIdx.x;
    for (int i = t; i < K; i += 256) c[i] = 0;
    __syncthreads();
    const int e0 = blk * CE, e1 = min(e0 + CE, E);
    for (int e = e0 + t; e < e1; e += 256)
        atomicAdd(&c[erow[e] >> 7], 1);
    __syncthreads();
    for (int k = t; k < K; k += 256)
        cnt_t[(size_t)blk * K + k] = c[k];
}

// per-key totals
__global__ __launch_bounds__(256) void keytot_kernel(
    const int* __restrict__ cnt_t, int* __restrict__ keytot, int K)
{
    int k = blockIdx.x * 256 + threadIdx.x;
    if (k < K) {
        int s = 0;
        for (int b = 0; b < NPB; ++b) s += cnt_t[(size_t)b * K + k];
        keytot[k] = s;
    }
}

// exclusive scan of keytot (K <= 1024), keybase[K] = total
__global__ __launch_bounds__(1024) void keyscan_kernel(
    const int* __restrict__ keytot, int* __restrict__ keybase, int K)
{
    __shared__ int wsum[16];
    const int t = threadIdx.x, wid = t >> 6, lane = t & 63;
    int c = (t < K) ? keytot[t] : 0;
    int x = c;
#pragma unroll
    for (int off = 1; off < 64; off <<= 1) {
        int y = __shfl_up(x, off);
        if (lane >= off) x += y;
    }
    if (lane == 63) wsum[wid] = x;
    __syncthreads();
    if (wid == 0 && lane < 16) {
        int wv = wsum[lane];
#pragma unroll
        for (int off = 1; off < 16; off <<= 1) {
            int y = __shfl_up(wv, off);
            if (lane >= off) wv += y;
        }
        wsum[lane] = wv;
    }
    __syncthreads();
    int woff = wid ? wsum[wid - 1] : 0;
    int incl = x + woff;
    if (t < K) keybase[t] = incl - c;
    if (t == 1023) keybase[K] = wsum[15];
}

// column scan: Sblk[blk][k] = keybase[k] + sum_{b<blk} cnt_t[b][k]
__global__ __launch_bounds__(256) void colscan_kernel(
    const int* __restrict__ cnt_t, const int* __restrict__ keybase,
    int* __restrict__ Sblk, int K)
{
    int k = blockIdx.x * 256 + threadIdx.x;
    if (k >= K) return;
    int run = keybase[k];
    for (int b = 0; b < NPB; ++b) {
        size_t idx = (size_t)b * K + k;
        int v = cnt_t[idx];
        Sblk[idx] = run;
        run += v;
    }
}

// pass 2: 8B stage records into private contiguous runs (~16 edges -> line merge)
// stage: hi = row(global), lo = (col:17 << 11) | q11, q11 = round(val*2^16) clamp 2047
__global__ __launch_bounds__(256) void scatterA_kernel(
    const float* __restrict__ vals, const int* __restrict__ erow,
    const int* __restrict__ ecol, const int* __restrict__ Sblk,
    unsigned long long* __restrict__ stage, int E, int CE, int K)
{
    __shared__ int lcur[KMAX];
    const int blk = blockIdx.x, t = threadIdx.x;
    for (int k = t; k < K; k += 256) lcur[k] = Sblk[(size_t)blk * K + k];
    __syncthreads();
    const int e0 = blk * CE, e1 = min(e0 + CE, E);
    for (int e = e0 + t; e < e1; e += 256) {
        int r = erow[e];
        unsigned q = (unsigned)__float2int_rn(vals[e] * 65536.f);
        if (q > 2047u) q = 2047u;
        unsigned lo = ((unsigned)ecol[e] << 11) | q;
        int pos = atomicAdd(&lcur[r >> 7], 1);
        stage[pos] = ((unsigned long long)(unsigned)r << 32) | lo;
    }
}

// pass 3: per rowblock -- chunk-sort into 4B records + segment bases
// rec = [row_local:7][col_local:14][q:11]
__global__ __launch_bounds__(256) void scatterB_kernel(
    const unsigned long long* __restrict__ stage, const int* __restrict__ keybase,
    unsigned* __restrict__ ep, int* __restrict__ segbase, int n, int nchunk)
{
    __shared__ int hist[8];
    __shared__ int cur[8];
    const int rb = blockIdx.x, t = threadIdx.x;
    const int r0 = rb * RBLK;
    if (r0 >= n) return;
    const int s0 = keybase[rb], s1 = keybase[rb + 1];
    if (t < 8) hist[t] = 0;
    __syncthreads();
    for (int i = s0 + t; i < s1; i += 256) {
        unsigned lo = (unsigned)stage[i];
        atomicAdd(&hist[(lo >> 11) >> CHUNK_SHIFT], 1);
    }
    __syncthreads();
    if (t == 0) {
        int run = s0;
        for (int j = 0; j < nchunk; ++j) {
            cur[j] = run;
            segbase[rb * (nchunk + 1) + j] = run;
            run += hist[j];
        }
        segbase[rb * (nchunk + 1) + nchunk] = run;   // == s1
    }
    __syncthreads();
    for (int i = s0 + t; i < s1; i += 256) {
        unsigned long long rec = stage[i];
        unsigned lo = (unsigned)rec;
        int row = (int)(rec >> 32);
        unsigned col = lo >> 11;
        int j = col >> CHUNK_SHIFT;
        int p = atomicAdd(&cur[j], 1);
        ep[p] = ((unsigned)(row - r0) << 25) | ((col & 0x3FFFu) << 11) | (lo & 0x7FFu);
    }
}

// ------- edge-parallel chunk-phased SPMM + APPNP: x_out = 0.9*A*x_in + 0.1*h -------
// block = 128 rows; fp32 LDS acc (stride 65 floats -> disjoint banks across rows);
// 16 groups x 16 lanes, each group streams edges of the current chunk segment.
__global__ __launch_bounds__(256) void spmm_kernel(
    const unsigned short* __restrict__ x_in, const unsigned short* __restrict__ h,
    unsigned short* __restrict__ x_out, const int* __restrict__ segbase,
    const unsigned* __restrict__ ep, int n, int nchunk)
{
    __shared__ float acc[RBLK * 65];
    const int rb = blockIdx.x;
    const int r0 = rb * RBLK;
    if (r0 >= n) return;
    const int nr = min(RBLK, n - r0);
    const int t = threadIdx.x;
    const int grp = t >> 4;
    const int li  = t & 15;

    for (int i = t; i < RBLK * 65; i += 256) acc[i] = 0.f;
    __syncthreads();

    const int* sb = segbase + rb * (nchunk + 1);
    for (int j = 0; j < nchunk; ++j) {
        const unsigned short* slab = x_in + ((size_t)j << (CHUNK_SHIFT + 6));
        const int s = sb[j], e = sb[j + 1];
        int i = s + grp;
        for (; i + 16 < e; i += 32) {
            unsigned p1 = ep[i];
            unsigned p2 = ep[i + 16];
            int   rl1 = p1 >> 25,             rl2 = p2 >> 25;
            int   cl1 = (p1 >> 11) & 0x3FFF,  cl2 = (p2 >> 11) & 0x3FFF;
            float v1 = (float)(p1 & 0x7FFu) * (1.f / 65536.f);
            float v2 = (float)(p2 & 0x7FFu) * (1.f / 65536.f);
            uint2 u1 = *reinterpret_cast<const uint2*>(slab + ((size_t)cl1 << 6) + (li << 2));
            uint2 u2 = *reinterpret_cast<const uint2*>(slab + ((size_t)cl2 << 6) + (li << 2));
            float* a1 = &acc[rl1 * 65 + li * 4];
            atomicAdd(a1 + 0, v1 * blo(u1.x));
            atomicAdd(a1 + 1, v1 * bhi(u1.x));
            atomicAdd(a1 + 2, v1 * blo(u1.y));
            atomicAdd(a1 + 3, v1 * bhi(u1.y));
            float* a2 = &acc[rl2 * 65 + li * 4];
            atomicAdd(a2 + 0, v2 * blo(u2.x));
            atomicAdd(a2 + 1, v2 * bhi(u2.x));
            atomicAdd(a2 + 2, v2 * blo(u2.y));
            atomicAdd(a2 + 3, v2 * bhi(u2.y));
        }
        if (i < e) {
            unsigned p = ep[i];
            int   rl = p >> 25;
            int   cl = (p >> 11) & 0x3FFF;
            float v = (float)(p & 0x7FFu) * (1.f / 65536.f);
            uint2 u = *reinterpret_cast<const uint2*>(slab + ((size_t)cl << 6) + (li << 2));
            float* ap = &acc[rl * 65 + li * 4];
            atomicAdd(ap + 0, v * blo(u.x));
            atomicAdd(ap + 1, v * bhi(u.x));
            atomicAdd(ap + 2, v * blo(u.y));
            atomicAdd(ap + 3, v * bhi(u.y));
        }
    }
    __syncthreads();

    for (int i = t; i < nr * 16; i += 256) {
        int lr = i >> 4, qq = i & 15;
        const float* ap = &acc[lr * 65 + qq * 4];
        size_t o = ((size_t)(r0 + lr) << 6) + (qq << 2);
        const unsigned* hp = reinterpret_cast<const unsigned*>(h + o);
        unsigned hx = hp[0], hy = hp[1];
        float r0f = (1.f - ALPHA_C) * ap[0] + ALPHA_C * blo(hx);
        float r1f = (1.f - ALPHA_C) * ap[1] + ALPHA_C * bhi(hx);
        float r2f = (1.f - ALPHA_C) * ap[2] + ALPHA_C * blo(hy);
        float r3f = (1.f - ALPHA_C) * ap[3] + ALPHA_C * bhi(hy);
        uint2 ou;
        ou.x = ((unsigned)f2b(r1f) << 16) | f2b(r0f);
        ou.y = ((unsigned)f2b(r3f) << 16) | f2b(r2f);
        *reinterpret_cast<uint2*>(x_out + o) = ou;
    }
}

// ---------------- log_softmax (bf16 in, fp32 out) ----------------
__global__ __launch_bounds__(256) void lsm_kernel(
    const unsigned short* __restrict__ x, float* __restrict__ out, int n)
{
    const int wid = threadIdx.x >> 6, lane = threadIdx.x & 63;
    const int r = blockIdx.x * 4 + wid;
    if (r >= n) return;
    float v = b2f(x[(size_t)r * NCLS + lane]);
    float m = v;
#pragma unroll
    for (int o = 32; o > 0; o >>= 1) m = fmaxf(m, __shfl_xor(m, o));
    float ex = expf(v - m);
    float s = ex;
#pragma unroll
    for (int o = 32; o > 0; o >>= 1) s += __shfl_xor(s, o);
    out[(size_t)r * NCLS + lane] = (v - m) - logf(s);
}

extern "C" void kernel_launch(void* const* d_in, const int* in_sizes, int n_in,
                              void* d_out, int out_size, void* d_ws, size_t ws_size,
                              hipStream_t stream)
{
    const float* feat = (const float*)d_in[0];
    const float* W1   = (const float*)d_in[1];
    const float* b1   = (const float*)d_in[2];
    const float* W2   = (const float*)d_in[3];
    const float* b2   = (const float*)d_in[4];
    const float* vals = (const float*)d_in[5];
    const int*   erow = (const int*)d_in[6];
    const int*   ecol = (const int*)d_in[7];
    const int N = in_sizes[0] / NFEAT;
    const int E = in_sizes[5];
    float* out = (float*)d_out;
    const int NRB    = (N + RBLK - 1) / RBLK;                 // 782
    const int NCHUNK = (N + (1 << CHUNK_SHIFT) - 1) >> CHUNK_SHIFT;   // 7
    const int CE = (E + NPB - 1) / NPB;
    const int NC = NRB * NPB;

    size_t off = 0;
    auto alloc = [&](size_t bytes) -> void* {
        void* p = (char*)d_ws + off;
        off += (bytes + 255) & ~(size_t)255;
        return p;
    };
    unsigned short*     h       = (unsigned short*)alloc((size_t)N * NCLS * 2);
    unsigned short*     xA      = (unsigned short*)alloc((size_t)N * NCLS * 2);
    unsigned short*     xB      = (unsigned short*)alloc((size_t)N * NCLS * 2);
    int*                segbase = (int*)alloc((size_t)NRB * (NCHUNK + 1) * 4);
    int*                cnt_t   = (int*)alloc((size_t)NC * 4);
    int*                Sblk    = (int*)alloc((size_t)NC * 4);
    int*                keytot  = (int*)alloc((size_t)NRB * 4);
    int*                keybase = (int*)alloc((size_t)(NRB + 1) * 4);
    unsigned*           ep      = (unsigned*)alloc((size_t)E * 4);
    unsigned long long* stage   = (unsigned long long*)alloc((size_t)E * 8);
    unsigned short*     W1T     = (unsigned short*)alloc((size_t)NHID * NFEAT * 2);
    unsigned short*     W2T     = (unsigned short*)alloc((size_t)NCLS * NHID * 2);
    (void)ws_size;

    // 0. weight transpose+convert (tiny)
    cvtT_kernel<<<(NFEAT * NHID + 255) / 256, 256, 0, stream>>>(W1, W1T, NFEAT, 8);
    cvtT_kernel<<<(NHID * NCLS + 255) / 256, 256, 0, stream>>>(W2, W2T, NHID, 6);

    // 1. fused MFMA MLP
    mlp_mfma_kernel<<<(N + 63) / 64, 256, 0, stream>>>(feat, W1T, b1, W2T, b2, h, N);

    // 2. 2-level scatter -> chunk-sorted 4B edge records + per-rowblock segments
    countP1_kernel<<<NPB, 256, 0, stream>>>(erow, cnt_t, E, CE, NRB);
    keytot_kernel<<<(NRB + 255) / 256, 256, 0, stream>>>(cnt_t, keytot, NRB);
    keyscan_kernel<<<1, 1024, 0, stream>>>(keytot, keybase, NRB);
    colscan_kernel<<<(NRB + 255) / 256, 256, 0, stream>>>(cnt_t, keybase, Sblk, NRB);
    scatterA_kernel<<<NPB, 256, 0, stream>>>(vals, erow, ecol, Sblk, stage, E, CE, NRB);
    scatterB_kernel<<<NRB, 256, 0, stream>>>(stage, keybase, ep, segbase, N, NCHUNK);

    // 3. K=10 edge-parallel chunk-phased propagation, ping-pong
    const unsigned short* cur = h;
    for (int i = 0; i < 10; ++i) {
        unsigned short* dst = (i & 1) ? xB : xA;
        spmm_kernel<<<NRB, 256, 0, stream>>>(cur, h, dst, segbase, ep, N, NCHUNK);
        cur = dst;
    }

    // 4. log_softmax
    lsm_kernel<<<(N + 3) / 4, 256, 0, stream>>>(cur, out, N);
}

// Round 11
// 2228.626 us; speedup vs baseline: 6.1539x; 6.1539x over previous
//
#include <hip/hip_runtime.h>
#include <hip/hip_bf16.h>
#include <math.h>

#define NNODES 100000
#define NFEAT 512
#define NHID 256
#define NCLS 64
#define ALPHA_C 0.1f
#define NBUCKET 512   // coarse row-buckets for 2-level scatter
#define NPB 512       // partition blocks (edge chunks)
#define RB2 196       // rows per bucket: ceil(100000/512)

typedef short s16x8 __attribute__((ext_vector_type(8)));
typedef float f32x4 __attribute__((ext_vector_type(4)));

__device__ inline unsigned short f2b(float f) {
    union { float f; unsigned u; } v; v.f = f;
    unsigned r = v.u + 0x7fff + ((v.u >> 16) & 1);   // RNE
    return (unsigned short)(r >> 16);
}
__device__ inline float b2f(unsigned short b) {
    return __uint_as_float((unsigned)b << 16);
}
__device__ inline float blo(unsigned u) { return __uint_as_float(u << 16); }
__device__ inline float bhi(unsigned u) { return __uint_as_float(u & 0xffff0000u); }

// ---------------- transpose+convert: dst[C][R] bf16 <- src[R][C] fp32 ----------------
__global__ __launch_bounds__(256) void cvtT_kernel(
    const float* __restrict__ src, unsigned short* __restrict__ dst, int R, int Clog2)
{
    int idx = blockIdx.x * 256 + threadIdx.x;
    int C = 1 << Clog2;
    if (idx < R * C) {
        int r = idx >> Clog2, c = idx & (C - 1);
        dst[(size_t)c * R + r] = f2b(src[idx]);
    }
}

// -------- fused MFMA MLP: h = relu(feat@W1+b1)@W2 + b2  (chunked bf16 out) --------
// h layout: [4 groups][N][16 ch]
#define HID_STRIDE 264   // 256 + 8 pad

__global__ __launch_bounds__(256) void mlp_mfma_kernel(
    const float* __restrict__ feat, const unsigned short* __restrict__ W1T,
    const float* __restrict__ b1, const unsigned short* __restrict__ W2T,
    const float* __restrict__ b2, unsigned short* __restrict__ h, int N)
{
    __shared__ unsigned short hid_s[64 * HID_STRIDE];
    const int tid  = threadIdx.x;
    const int w    = tid >> 6;
    const int lane = tid & 63;
    const int lr   = lane & 15;
    const int lh   = lane >> 4;
    const int m0   = blockIdx.x * 64;

    f32x4 acc[4][4];
#pragma unroll
    for (int i = 0; i < 4; ++i)
#pragma unroll
        for (int j = 0; j < 4; ++j) acc[i][j] = (f32x4)0.f;

    const float* arow[4];
#pragma unroll
    for (int mi = 0; mi < 4; ++mi) {
        int r = m0 + mi * 16 + lr;
        if (r > N - 1) r = N - 1;
        arow[mi] = feat + (size_t)r * NFEAT;
    }
    const unsigned short* brow[4];
#pragma unroll
    for (int nj = 0; nj < 4; ++nj)
        brow[nj] = W1T + (size_t)(w * 64 + nj * 16 + lr) * NFEAT;

    for (int kb = 0; kb < NFEAT; kb += 32) {
        const int k0 = kb + lh * 8;
        s16x8 afr[4], bfr[4];
#pragma unroll
        for (int mi = 0; mi < 4; ++mi) {
            float4 f0 = *reinterpret_cast<const float4*>(arow[mi] + k0);
            float4 f1 = *reinterpret_cast<const float4*>(arow[mi] + k0 + 4);
            s16x8 a;
            a[0] = f2b(f0.x); a[1] = f2b(f0.y); a[2] = f2b(f0.z); a[3] = f2b(f0.w);
            a[4] = f2b(f1.x); a[5] = f2b(f1.y); a[6] = f2b(f1.z); a[7] = f2b(f1.w);
            afr[mi] = a;
        }
#pragma unroll
        for (int nj = 0; nj < 4; ++nj)
            bfr[nj] = *reinterpret_cast<const s16x8*>(brow[nj] + k0);
#pragma unroll
        for (int mi = 0; mi < 4; ++mi)
#pragma unroll
            for (int nj = 0; nj < 4; ++nj)
                acc[mi][nj] = __builtin_amdgcn_mfma_f32_16x16x32_bf16(
                    afr[mi], bfr[nj], acc[mi][nj], 0, 0, 0);
    }

#pragma unroll
    for (int nj = 0; nj < 4; ++nj) {
        int col = w * 64 + nj * 16 + lr;
        float bias = b1[col];
#pragma unroll
        for (int mi = 0; mi < 4; ++mi)
#pragma unroll
            for (int q = 0; q < 4; ++q) {
                int row = mi * 16 + lh * 4 + q;
                hid_s[row * HID_STRIDE + col] = f2b(fmaxf(acc[mi][nj][q] + bias, 0.f));
            }
    }
    __syncthreads();

    f32x4 acc2[4];
#pragma unroll
    for (int i = 0; i < 4; ++i) acc2[i] = (f32x4)0.f;
    const int cw = w * 16;
    const unsigned short* b2row = W2T + (size_t)(cw + lr) * NHID;
    for (int ks = 0; ks < NHID; ks += 32) {
        int k0 = ks + lh * 8;
        s16x8 bfr = *reinterpret_cast<const s16x8*>(b2row + k0);
#pragma unroll
        for (int mi = 0; mi < 4; ++mi) {
            s16x8 afr = *reinterpret_cast<const s16x8*>(
                &hid_s[(mi * 16 + lr) * HID_STRIDE + k0]);
            acc2[mi] = __builtin_amdgcn_mfma_f32_16x16x32_bf16(afr, bfr, acc2[mi], 0, 0, 0);
        }
    }
    int col = cw + lr;
    float bias2 = b2[col];
    // chunked write: h[group][row][ch16]
    const size_t cbase = (size_t)(col >> 4) * N * 16 + (col & 15);
#pragma unroll
    for (int mi = 0; mi < 4; ++mi)
#pragma unroll
        for (int q = 0; q < 4; ++q) {
            int row = m0 + mi * 16 + lh * 4 + q;
            if (row < N) h[cbase + (size_t)row * 16] = f2b(acc2[mi][q] + bias2);
        }
}

// ---------------- 3-phase scan ----------------
__global__ __launch_bounds__(1024) void scanA_kernel(
    const int* __restrict__ cnt, int* __restrict__ excl, int* __restrict__ partials, int n)
{
    __shared__ int wsum[16];
    const int t = threadIdx.x, wid = t >> 6, lane = t & 63;
    const int i = blockIdx.x * 1024 + t;
    int c = (i < n) ? cnt[i] : 0;
    int x = c;
#pragma unroll
    for (int off = 1; off < 64; off <<= 1) {
        int y = __shfl_up(x, off);
        if (lane >= off) x += y;
    }
    if (lane == 63) wsum[wid] = x;
    __syncthreads();
    if (wid == 0 && lane < 16) {
        int wv = wsum[lane];
#pragma unroll
        for (int off = 1; off < 16; off <<= 1) {
            int y = __shfl_up(wv, off);
            if (lane >= off) wv += y;
        }
        wsum[lane] = wv;
    }
    __syncthreads();
    int woff = wid ? wsum[wid - 1] : 0;
    int incl = x + woff;
    if (i < n) excl[i] = incl - c;
    if (t == 1023) partials[blockIdx.x] = incl;
}

__global__ __launch_bounds__(256) void scanB_kernel(
    int* __restrict__ partials, int* __restrict__ total_out, int nb, int n)
{
    __shared__ int s[256];
    const int t = threadIdx.x;
    int v = (t < nb) ? partials[t] : 0;
    s[t] = v;
    __syncthreads();
    for (int off = 1; off < 256; off <<= 1) {
        int y = (t >= off) ? s[t - off] : 0;
        __syncthreads();
        s[t] += y;
        __syncthreads();
    }
    partials[t] = s[t] - v;
    if (t == 255) total_out[n] = s[255];
}

__global__ __launch_bounds__(1024) void scanC_kernel(
    int* __restrict__ arr, const int* __restrict__ partials, int n)
{
    const int i = blockIdx.x * 1024 + threadIdx.x;
    if (i < n) arr[i] += partials[blockIdx.x];
}

// ------------- 2-level scatter (round-8 proven) -------------
__global__ __launch_bounds__(256) void countP1_kernel(
    const int* __restrict__ erow, int* __restrict__ cnts, int E, int CE)
{
    __shared__ int c[NBUCKET];
    const int blk = blockIdx.x, t = threadIdx.x;
    for (int i = t; i < NBUCKET; i += 256) c[i] = 0;
    __syncthreads();
    const int e0 = blk * CE, e1 = min(e0 + CE, E);
    for (int e = e0 + t; e < e1; e += 256)
        atomicAdd(&c[erow[e] / RB2], 1);
    __syncthreads();
    for (int b = t; b < NBUCKET; b += 256)
        cnts[(size_t)b * NPB + blk] = c[b];
}

__global__ __launch_bounds__(256) void scatterA_kernel(
    const float* __restrict__ vals, const int* __restrict__ erow,
    const int* __restrict__ ecol, const int* __restrict__ S,
    unsigned long long* __restrict__ stage, int E, int CE)
{
    __shared__ int lcur[NBUCKET];
    const int blk = blockIdx.x, t = threadIdx.x;
    for (int b = t; b < NBUCKET; b += 256) lcur[b] = S[(size_t)b * NPB + blk];
    __syncthreads();
    const int e0 = blk * CE, e1 = min(e0 + CE, E);
    for (int e = e0 + t; e < e1; e += 256) {
        int r = erow[e];
        unsigned q = (unsigned)__float2int_rn(vals[e] * 1048576.f);
        if (q > 32767u) q = 32767u;
        unsigned lo = ((unsigned)ecol[e] << 15) | q;
        int pos = atomicAdd(&lcur[r / RB2], 1);
        stage[pos] = ((unsigned long long)(unsigned)r << 32) | lo;
    }
}

__global__ __launch_bounds__(256) void scatterB_kernel(
    const unsigned long long* __restrict__ stage, const int* __restrict__ S,
    unsigned* __restrict__ ep, int* __restrict__ row_ptr, int n, int E)
{
    __shared__ int hcnt[256];
    __shared__ int lcur[256];
    const int b = blockIdx.x, t = threadIdx.x;
    if (b == 0 && t == 0) row_ptr[n] = E;
    const int r0 = b * RB2;
    if (r0 >= n) return;
    const int nr = min(RB2, n - r0);
    const int s0 = S[(size_t)b * NPB];
    const int s1 = S[(size_t)(b + 1) * NPB];
    hcnt[t] = 0;
    __syncthreads();
    for (int i = s0 + t; i < s1; i += 256)
        atomicAdd(&hcnt[(int)(stage[i] >> 32) - r0], 1);
    __syncthreads();
    int v = hcnt[t];
    lcur[t] = v;
    __syncthreads();
    for (int off = 1; off < 256; off <<= 1) {
        int y = (t >= off) ? lcur[t - off] : 0;
        __syncthreads();
        lcur[t] += y;
        __syncthreads();
    }
    int excl = lcur[t] - v;
    if (t < nr) row_ptr[r0 + t] = s0 + excl;
    __syncthreads();
    lcur[t] = s0 + excl;
    __syncthreads();
    for (int i = s0 + t; i < s1; i += 256) {
        unsigned long long rec = stage[i];
        int r = (int)(rec >> 32);
        int p = atomicAdd(&lcur[r - r0], 1);
        ep[p] = (unsigned)rec;
    }
}

// --- channel-grouped SPMM + APPNP: og = 0.9*A*xg + 0.1*hg  (one 16-ch slab) ---
// wave = row; 8 edge slots x 8 lanes; lane loads 4B (2ch); 16 edges in flight.
// slab = [N][16] bf16 = 3.2MB -> per-XCD-L2 resident.
__global__ __launch_bounds__(256) void spmm_kernel(
    const unsigned short* __restrict__ xg, const unsigned short* __restrict__ hg,
    unsigned short* __restrict__ og, const int* __restrict__ row_ptr,
    const unsigned* __restrict__ ep, int n)
{
    const int wid = threadIdx.x >> 6, lane = threadIdx.x & 63;
    const int r = blockIdx.x * 4 + wid;
    if (r >= n) return;
    const int sub = lane >> 3;   // edge slot 0..7
    const int li  = lane & 7;    // uint index: channels [2li, 2li+1]
    const int s = row_ptr[r], e_end = row_ptr[r + 1];

    float aA0 = 0.f, aA1 = 0.f, aB0 = 0.f, aB1 = 0.f;
    int e0 = s;
    for (; e0 + 16 <= e_end; e0 += 16) {
        unsigned p1 = __builtin_nontemporal_load(ep + e0 + sub);
        unsigned p2 = __builtin_nontemporal_load(ep + e0 + 8 + sub);
        int   c1 = (int)(p1 >> 15);
        int   c2 = (int)(p2 >> 15);
        float v1 = (float)(p1 & 0x7fffu) * (1.f / 1048576.f);
        float v2 = (float)(p2 & 0x7fffu) * (1.f / 1048576.f);
        unsigned u1 = *reinterpret_cast<const unsigned*>(xg + ((size_t)c1 << 4) + (li << 1));
        unsigned u2 = *reinterpret_cast<const unsigned*>(xg + ((size_t)c2 << 4) + (li << 1));
        aA0 += v1 * blo(u1); aA1 += v1 * bhi(u1);
        aB0 += v2 * blo(u2); aB1 += v2 * bhi(u2);
    }
    for (; e0 < e_end; e0 += 8) {
        int e = e0 + sub;
        if (e < e_end) {
            unsigned p = __builtin_nontemporal_load(ep + e);
            int   c = (int)(p >> 15);
            float v = (float)(p & 0x7fffu) * (1.f / 1048576.f);
            unsigned u = *reinterpret_cast<const unsigned*>(xg + ((size_t)c << 4) + (li << 1));
            aA0 += v * blo(u); aA1 += v * bhi(u);
        }
    }
    float a0 = aA0 + aB0, a1 = aA1 + aB1;
#pragma unroll
    for (int off = 8; off < 64; off <<= 1) {
        a0 += __shfl_xor(a0, off);
        a1 += __shfl_xor(a1, off);
    }
    if (sub == 0) {
        size_t o = ((size_t)r << 4) + (li << 1);
        unsigned hu = *reinterpret_cast<const unsigned*>(hg + o);
        float r0 = (1.f - ALPHA_C) * a0 + ALPHA_C * blo(hu);
        float r1 = (1.f - ALPHA_C) * a1 + ALPHA_C * bhi(hu);
        *reinterpret_cast<unsigned*>(og + o) = ((unsigned)f2b(r1) << 16) | f2b(r0);
    }
}

// ---------------- log_softmax (chunked bf16 in, fp32 row-major out) ----------------
__global__ __launch_bounds__(256) void lsm_kernel(
    const unsigned short* __restrict__ x, float* __restrict__ out, int n)
{
    const int wid = threadIdx.x >> 6, lane = threadIdx.x & 63;
    const int r = blockIdx.x * 4 + wid;
    if (r >= n) return;
    float v = b2f(x[(size_t)(lane >> 4) * n * 16 + (size_t)r * 16 + (lane & 15)]);
    float m = v;
#pragma unroll
    for (int o = 32; o > 0; o >>= 1) m = fmaxf(m, __shfl_xor(m, o));
    float ex = expf(v - m);
    float s = ex;
#pragma unroll
    for (int o = 32; o > 0; o >>= 1) s += __shfl_xor(s, o);
    out[(size_t)r * NCLS + lane] = (v - m) - logf(s);
}

extern "C" void kernel_launch(void* const* d_in, const int* in_sizes, int n_in,
                              void* d_out, int out_size, void* d_ws, size_t ws_size,
                              hipStream_t stream)
{
    const float* feat = (const float*)d_in[0];
    const float* W1   = (const float*)d_in[1];
    const float* b1   = (const float*)d_in[2];
    const float* W2   = (const float*)d_in[3];
    const float* b2   = (const float*)d_in[4];
    const float* vals = (const float*)d_in[5];
    const int*   erow = (const int*)d_in[6];
    const int*   ecol = (const int*)d_in[7];
    const int N = in_sizes[0] / NFEAT;
    const int E = in_sizes[5];
    float* out = (float*)d_out;
    const int CE = (E + NPB - 1) / NPB;
    const int NC = NBUCKET * NPB;

    size_t off = 0;
    auto alloc = [&](size_t bytes) -> void* {
        void* p = (char*)d_ws + off;
        off += (bytes + 255) & ~(size_t)255;
        return p;
    };
    unsigned short*     h        = (unsigned short*)alloc((size_t)N * NCLS * 2);
    unsigned short*     xA       = (unsigned short*)alloc((size_t)N * NCLS * 2);
    unsigned short*     xB       = (unsigned short*)alloc((size_t)N * NCLS * 2);
    int*                row_ptr  = (int*)alloc((size_t)(N + 1) * 4);
    int*                cnts     = (int*)alloc((size_t)NC * 4);
    int*                S        = (int*)alloc((size_t)(NC + 1) * 4);
    int*                partials = (int*)alloc(256 * 4);
    unsigned*           ep       = (unsigned*)alloc((size_t)E * 4);
    unsigned long long* stage    = (unsigned long long*)alloc((size_t)E * 8);
    unsigned short*     W1T      = (unsigned short*)alloc((size_t)NHID * NFEAT * 2);
    unsigned short*     W2T      = (unsigned short*)alloc((size_t)NCLS * NHID * 2);
    (void)ws_size;

    // 0. weight transpose+convert (tiny)
    cvtT_kernel<<<(NFEAT * NHID + 255) / 256, 256, 0, stream>>>(W1, W1T, NFEAT, 8);
    cvtT_kernel<<<(NHID * NCLS + 255) / 256, 256, 0, stream>>>(W2, W2T, NHID, 6);

    // 1. fused MFMA MLP (chunked h)
    mlp_mfma_kernel<<<(N + 63) / 64, 256, 0, stream>>>(feat, W1T, b1, W2T, b2, h, N);

    // 2. 2-level scatter -> CSR (round-8 proven)
    countP1_kernel<<<NPB, 256, 0, stream>>>(erow, cnts, E, CE);
    scanA_kernel<<<NC / 1024, 1024, 0, stream>>>(cnts, S, partials, NC);
    scanB_kernel<<<1, 256, 0, stream>>>(partials, S, 256, NC);
    scanC_kernel<<<NC / 1024, 1024, 0, stream>>>(S, partials, NC);
    scatterA_kernel<<<NPB, 256, 0, stream>>>(vals, erow, ecol, S, stage, E, CE);
    scatterB_kernel<<<NBUCKET, 256, 0, stream>>>(stage, S, ep, row_ptr, N, E);

    // 3. channel-grouped propagation: per 16-ch group, 10 iterations (L2-resident slab)
    const int gprop = (N + 3) / 4;
    for (int g = 0; g < 4; ++g) {
        const size_t goff = (size_t)g * N * 16;
        const unsigned short* cur = h + goff;
        for (int i = 0; i < 10; ++i) {
            unsigned short* dst = ((i & 1) ? xB : xA) + goff;
            spmm_kernel<<<gprop, 256, 0, stream>>>(cur, h + goff, dst, row_ptr, ep, N);
            cur = dst;
        }
    }

    // 4. log_softmax (final state in xB, chunked)
    lsm_kernel<<<gprop, 256, 0, stream>>>(xB, out, N);
}

// Round 12
// 1080.810 us; speedup vs baseline: 12.6892x; 2.0620x over previous
//
#include <hip/hip_runtime.h>
#include <hip/hip_bf16.h>
#include <math.h>

#define NNODES 100000
#define NFEAT 512
#define NHID 256
#define NCLS 64
#define ALPHA_C 0.1f
#define NBUCKET 512   // coarse row-buckets for 2-level scatter
#define NPB 512       // partition blocks (edge chunks)
#define RB2 196       // rows per bucket: ceil(100000/512)

typedef short s16x8 __attribute__((ext_vector_type(8)));
typedef float f32x4 __attribute__((ext_vector_type(4)));

__device__ inline unsigned short f2b(float f) {
    union { float f; unsigned u; } v; v.f = f;
    unsigned r = v.u + 0x7fff + ((v.u >> 16) & 1);   // RNE
    return (unsigned short)(r >> 16);
}
__device__ inline float b2f(unsigned short b) {
    return __uint_as_float((unsigned)b << 16);
}
__device__ inline float blo(unsigned u) { return __uint_as_float(u << 16); }
__device__ inline float bhi(unsigned u) { return __uint_as_float(u & 0xffff0000u); }

// ---------------- transpose+convert: dst[C][R] bf16 <- src[R][C] fp32 ----------------
__global__ __launch_bounds__(256) void cvtT_kernel(
    const float* __restrict__ src, unsigned short* __restrict__ dst, int R, int Clog2)
{
    int idx = blockIdx.x * 256 + threadIdx.x;
    int C = 1 << Clog2;
    if (idx < R * C) {
        int r = idx >> Clog2, c = idx & (C - 1);
        dst[(size_t)c * R + r] = f2b(src[idx]);
    }
}

// ---------------- streaming convert: feat fp32 -> bf16 (same layout) ----------------
__global__ __launch_bounds__(256) void cvtF_kernel(
    const float* __restrict__ src, unsigned short* __restrict__ dst, long n8)
{
    long i = (long)blockIdx.x * 256 + threadIdx.x;
    if (i < n8) {
        const float4* s = reinterpret_cast<const float4*>(src + i * 8);
        float4 f0 = s[0], f1 = s[1];
        s16x8 a;
        a[0] = f2b(f0.x); a[1] = f2b(f0.y); a[2] = f2b(f0.z); a[3] = f2b(f0.w);
        a[4] = f2b(f1.x); a[5] = f2b(f1.y); a[6] = f2b(f1.z); a[7] = f2b(f1.w);
        *reinterpret_cast<s16x8*>(dst + i * 8) = a;
    }
}

// ---------------- fused MFMA MLP (fp32-feat fallback): h = relu(f@W1+b1)@W2+b2 -------
#define HID_STRIDE 264   // 256 + 8 pad

__global__ __launch_bounds__(256) void mlp_mfma_kernel(
    const float* __restrict__ feat, const unsigned short* __restrict__ W1T,
    const float* __restrict__ b1, const unsigned short* __restrict__ W2T,
    const float* __restrict__ b2, unsigned short* __restrict__ h, int N)
{
    __shared__ unsigned short hid_s[64 * HID_STRIDE];
    const int tid  = threadIdx.x;
    const int w    = tid >> 6;
    const int lane = tid & 63;
    const int lr   = lane & 15;
    const int lh   = lane >> 4;
    const int m0   = blockIdx.x * 64;

    f32x4 acc[4][4];
#pragma unroll
    for (int i = 0; i < 4; ++i)
#pragma unroll
        for (int j = 0; j < 4; ++j) acc[i][j] = (f32x4)0.f;

    const float* arow[4];
#pragma unroll
    for (int mi = 0; mi < 4; ++mi) {
        int r = m0 + mi * 16 + lr;
        if (r > N - 1) r = N - 1;
        arow[mi] = feat + (size_t)r * NFEAT;
    }
    const unsigned short* brow[4];
#pragma unroll
    for (int nj = 0; nj < 4; ++nj)
        brow[nj] = W1T + (size_t)(w * 64 + nj * 16 + lr) * NFEAT;

    for (int kb = 0; kb < NFEAT; kb += 32) {
        const int k0 = kb + lh * 8;
        s16x8 afr[4], bfr[4];
#pragma unroll
        for (int mi = 0; mi < 4; ++mi) {
            float4 f0 = *reinterpret_cast<const float4*>(arow[mi] + k0);
            float4 f1 = *reinterpret_cast<const float4*>(arow[mi] + k0 + 4);
            s16x8 a;
            a[0] = f2b(f0.x); a[1] = f2b(f0.y); a[2] = f2b(f0.z); a[3] = f2b(f0.w);
            a[4] = f2b(f1.x); a[5] = f2b(f1.y); a[6] = f2b(f1.z); a[7] = f2b(f1.w);
            afr[mi] = a;
        }
#pragma unroll
        for (int nj = 0; nj < 4; ++nj)
            bfr[nj] = *reinterpret_cast<const s16x8*>(brow[nj] + k0);
#pragma unroll
        for (int mi = 0; mi < 4; ++mi)
#pragma unroll
            for (int nj = 0; nj < 4; ++nj)
                acc[mi][nj] = __builtin_amdgcn_mfma_f32_16x16x32_bf16(
                    afr[mi], bfr[nj], acc[mi][nj], 0, 0, 0);
    }

#pragma unroll
    for (int nj = 0; nj < 4; ++nj) {
        int col = w * 64 + nj * 16 + lr;
        float bias = b1[col];
#pragma unroll
        for (int mi = 0; mi < 4; ++mi)
#pragma unroll
            for (int q = 0; q < 4; ++q) {
                int row = mi * 16 + lh * 4 + q;
                hid_s[row * HID_STRIDE + col] = f2b(fmaxf(acc[mi][nj][q] + bias, 0.f));
            }
    }
    __syncthreads();

    f32x4 acc2[4];
#pragma unroll
    for (int i = 0; i < 4; ++i) acc2[i] = (f32x4)0.f;
    const int cw = w * 16;
    const unsigned short* b2row = W2T + (size_t)(cw + lr) * NHID;
    for (int ks = 0; ks < NHID; ks += 32) {
        int k0 = ks + lh * 8;
        s16x8 bfr = *reinterpret_cast<const s16x8*>(b2row + k0);
#pragma unroll
        for (int mi = 0; mi < 4; ++mi) {
            s16x8 afr = *reinterpret_cast<const s16x8*>(
                &hid_s[(mi * 16 + lr) * HID_STRIDE + k0]);
            acc2[mi] = __builtin_amdgcn_mfma_f32_16x16x32_bf16(afr, bfr, acc2[mi], 0, 0, 0);
        }
    }
    int col = cw + lr;
    float bias2 = b2[col];
#pragma unroll
    for (int mi = 0; mi < 4; ++mi)
#pragma unroll
        for (int q = 0; q < 4; ++q) {
            int row = m0 + mi * 16 + lh * 4 + q;
            if (row < N) h[(size_t)row * NCLS + col] = f2b(acc2[mi][q] + bias2);
        }
}

// ---------------- fused MFMA MLP (bf16-feat fast path) ----------------
__global__ __launch_bounds__(256) void mlp_mfma_bf16_kernel(
    const unsigned short* __restrict__ feat, const unsigned short* __restrict__ W1T,
    const float* __restrict__ b1, const unsigned short* __restrict__ W2T,
    const float* __restrict__ b2, unsigned short* __restrict__ h, int N)
{
    __shared__ unsigned short hid_s[64 * HID_STRIDE];
    const int tid  = threadIdx.x;
    const int w    = tid >> 6;
    const int lane = tid & 63;
    const int lr   = lane & 15;
    const int lh   = lane >> 4;
    const int m0   = blockIdx.x * 64;

    f32x4 acc[4][4];
#pragma unroll
    for (int i = 0; i < 4; ++i)
#pragma unroll
        for (int j = 0; j < 4; ++j) acc[i][j] = (f32x4)0.f;

    const unsigned short* arow[4];
#pragma unroll
    for (int mi = 0; mi < 4; ++mi) {
        int r = m0 + mi * 16 + lr;
        if (r > N - 1) r = N - 1;
        arow[mi] = feat + (size_t)r * NFEAT;
    }
    const unsigned short* brow[4];
#pragma unroll
    for (int nj = 0; nj < 4; ++nj)
        brow[nj] = W1T + (size_t)(w * 64 + nj * 16 + lr) * NFEAT;

    for (int kb = 0; kb < NFEAT; kb += 32) {
        const int k0 = kb + lh * 8;
        s16x8 afr[4], bfr[4];
#pragma unroll
        for (int mi = 0; mi < 4; ++mi)
            afr[mi] = *reinterpret_cast<const s16x8*>(arow[mi] + k0);
#pragma unroll
        for (int nj = 0; nj < 4; ++nj)
            bfr[nj] = *reinterpret_cast<const s16x8*>(brow[nj] + k0);
#pragma unroll
        for (int mi = 0; mi < 4; ++mi)
#pragma unroll
            for (int nj = 0; nj < 4; ++nj)
                acc[mi][nj] = __builtin_amdgcn_mfma_f32_16x16x32_bf16(
                    afr[mi], bfr[nj], acc[mi][nj], 0, 0, 0);
    }

#pragma unroll
    for (int nj = 0; nj < 4; ++nj) {
        int col = w * 64 + nj * 16 + lr;
        float bias = b1[col];
#pragma unroll
        for (int mi = 0; mi < 4; ++mi)
#pragma unroll
            for (int q = 0; q < 4; ++q) {
                int row = mi * 16 + lh * 4 + q;
                hid_s[row * HID_STRIDE + col] = f2b(fmaxf(acc[mi][nj][q] + bias, 0.f));
            }
    }
    __syncthreads();

    f32x4 acc2[4];
#pragma unroll
    for (int i = 0; i < 4; ++i) acc2[i] = (f32x4)0.f;
    const int cw = w * 16;
    const unsigned short* b2row = W2T + (size_t)(cw + lr) * NHID;
    for (int ks = 0; ks < NHID; ks += 32) {
        int k0 = ks + lh * 8;
        s16x8 bfr = *reinterpret_cast<const s16x8*>(b2row + k0);
#pragma unroll
        for (int mi = 0; mi < 4; ++mi) {
            s16x8 afr = *reinterpret_cast<const s16x8*>(
                &hid_s[(mi * 16 + lr) * HID_STRIDE + k0]);
            acc2[mi] = __builtin_amdgcn_mfma_f32_16x16x32_bf16(afr, bfr, acc2[mi], 0, 0, 0);
        }
    }
    int col = cw + lr;
    float bias2 = b2[col];
#pragma unroll
    for (int mi = 0; mi < 4; ++mi)
#pragma unroll
        for (int q = 0; q < 4; ++q) {
            int row = m0 + mi * 16 + lh * 4 + q;
            if (row < N) h[(size_t)row * NCLS + col] = f2b(acc2[mi][q] + bias2);
        }
}

// ---------------- 3-phase scan ----------------
__global__ __launch_bounds__(1024) void scanA_kernel(
    const int* __restrict__ cnt, int* __restrict__ excl, int* __restrict__ partials, int n)
{
    __shared__ int wsum[16];
    const int t = threadIdx.x, wid = t >> 6, lane = t & 63;
    const int i = blockIdx.x * 1024 + t;
    int c = (i < n) ? cnt[i] : 0;
    int x = c;
#pragma unroll
    for (int off = 1; off < 64; off <<= 1) {
        int y = __shfl_up(x, off);
        if (lane >= off) x += y;
    }
    if (lane == 63) wsum[wid] = x;
    __syncthreads();
    if (wid == 0 && lane < 16) {
        int wv = wsum[lane];
#pragma unroll
        for (int off = 1; off < 16; off <<= 1) {
            int y = __shfl_up(wv, off);
            if (lane >= off) wv += y;
        }
        wsum[lane] = wv;
    }
    __syncthreads();
    int woff = wid ? wsum[wid - 1] : 0;
    int incl = x + woff;
    if (i < n) excl[i] = incl - c;
    if (t == 1023) partials[blockIdx.x] = incl;
}

__global__ __launch_bounds__(256) void scanB_kernel(
    int* __restrict__ partials, int* __restrict__ total_out, int nb, int n)
{
    __shared__ int s[256];
    const int t = threadIdx.x;
    int v = (t < nb) ? partials[t] : 0;
    s[t] = v;
    __syncthreads();
    for (int off = 1; off < 256; off <<= 1) {
        int y = (t >= off) ? s[t - off] : 0;
        __syncthreads();
        s[t] += y;
        __syncthreads();
    }
    partials[t] = s[t] - v;
    if (t == 255) total_out[n] = s[255];
}

__global__ __launch_bounds__(1024) void scanC_kernel(
    int* __restrict__ arr, const int* __restrict__ partials, int n)
{
    const int i = blockIdx.x * 1024 + threadIdx.x;
    if (i < n) arr[i] += partials[blockIdx.x];
}

// ------------- 2-level scatter (round-8 proven) -------------
__global__ __launch_bounds__(256) void countP1_kernel(
    const int* __restrict__ erow, int* __restrict__ cnts, int E, int CE)
{
    __shared__ int c[NBUCKET];
    const int blk = blockIdx.x, t = threadIdx.x;
    for (int i = t; i < NBUCKET; i += 256) c[i] = 0;
    __syncthreads();
    const int e0 = blk * CE, e1 = min(e0 + CE, E);
    for (int e = e0 + t; e < e1; e += 256)
        atomicAdd(&c[erow[e] / RB2], 1);
    __syncthreads();
    for (int b = t; b < NBUCKET; b += 256)
        cnts[(size_t)b * NPB + blk] = c[b];
}

__global__ __launch_bounds__(256) void scatterA_kernel(
    const float* __restrict__ vals, const int* __restrict__ erow,
    const int* __restrict__ ecol, const int* __restrict__ S,
    unsigned long long* __restrict__ stage, int E, int CE)
{
    __shared__ int lcur[NBUCKET];
    const int blk = blockIdx.x, t = threadIdx.x;
    for (int b = t; b < NBUCKET; b += 256) lcur[b] = S[(size_t)b * NPB + blk];
    __syncthreads();
    const int e0 = blk * CE, e1 = min(e0 + CE, E);
    for (int e = e0 + t; e < e1; e += 256) {
        int r = erow[e];
        unsigned q = (unsigned)__float2int_rn(vals[e] * 1048576.f);
        if (q > 32767u) q = 32767u;
        unsigned lo = ((unsigned)ecol[e] << 15) | q;
        int pos = atomicAdd(&lcur[r / RB2], 1);
        stage[pos] = ((unsigned long long)(unsigned)r << 32) | lo;
    }
}

__global__ __launch_bounds__(256) void scatterB_kernel(
    const unsigned long long* __restrict__ stage, const int* __restrict__ S,
    unsigned* __restrict__ ep, int* __restrict__ row_ptr, int n, int E)
{
    __shared__ int hcnt[256];
    __shared__ int lcur[256];
    const int b = blockIdx.x, t = threadIdx.x;
    if (b == 0 && t == 0) row_ptr[n] = E;
    const int r0 = b * RB2;
    if (r0 >= n) return;
    const int nr = min(RB2, n - r0);
    const int s0 = S[(size_t)b * NPB];
    const int s1 = S[(size_t)(b + 1) * NPB];
    hcnt[t] = 0;
    __syncthreads();
    for (int i = s0 + t; i < s1; i += 256)
        atomicAdd(&hcnt[(int)(stage[i] >> 32) - r0], 1);
    __syncthreads();
    int v = hcnt[t];
    lcur[t] = v;
    __syncthreads();
    for (int off = 1; off < 256; off <<= 1) {
        int y = (t >= off) ? lcur[t - off] : 0;
        __syncthreads();
        lcur[t] += y;
        __syncthreads();
    }
    int excl = lcur[t] - v;
    if (t < nr) row_ptr[r0 + t] = s0 + excl;
    __syncthreads();
    lcur[t] = s0 + excl;
    __syncthreads();
    for (int i = s0 + t; i < s1; i += 256) {
        unsigned long long rec = stage[i];
        int r = (int)(rec >> 32);
        int p = atomicAdd(&lcur[r - r0], 1);
        ep[p] = (unsigned)rec;
    }
}

// ------- SPMM + APPNP update (bf16 state): x_out = 0.9*A*x_in + 0.1*h -------
// wave = 4 edge-groups x 16 lanes; 16 edges in flight (round-8 proven shape)
__global__ __launch_bounds__(256) void spmm_kernel(
    const unsigned short* __restrict__ x_in, const unsigned short* __restrict__ h,
    unsigned short* __restrict__ x_out, const int* __restrict__ row_ptr,
    const unsigned* __restrict__ ep, int n)
{
    const int wid = threadIdx.x >> 6, lane = threadIdx.x & 63;
    const int r = blockIdx.x * 4 + wid;
    if (r >= n) return;
    const int g  = lane >> 4;
    const int li = lane & 15;
    const int s = row_ptr[r], e_end = row_ptr[r + 1];

    float aA0 = 0.f, aA1 = 0.f, aA2 = 0.f, aA3 = 0.f;
    float aB0 = 0.f, aB1 = 0.f, aB2 = 0.f, aB3 = 0.f;
    float aC0 = 0.f, aC1 = 0.f, aC2 = 0.f, aC3 = 0.f;
    float aD0 = 0.f, aD1 = 0.f, aD2 = 0.f, aD3 = 0.f;
    int e0 = s;
    for (; e0 + 16 <= e_end; e0 += 16) {
        unsigned p1 = __builtin_nontemporal_load(ep + e0 + g);
        unsigned p2 = __builtin_nontemporal_load(ep + e0 + 4 + g);
        unsigned p3 = __builtin_nontemporal_load(ep + e0 + 8 + g);
        unsigned p4 = __builtin_nontemporal_load(ep + e0 + 12 + g);
        int   c1 = (int)(p1 >> 15);
        int   c2 = (int)(p2 >> 15);
        int   c3 = (int)(p3 >> 15);
        int   c4 = (int)(p4 >> 15);
        float v1 = (float)(p1 & 0x7fffu) * (1.f / 1048576.f);
        float v2 = (float)(p2 & 0x7fffu) * (1.f / 1048576.f);
        float v3 = (float)(p3 & 0x7fffu) * (1.f / 1048576.f);
        float v4 = (float)(p4 & 0x7fffu) * (1.f / 1048576.f);
        uint2 u1 = *reinterpret_cast<const uint2*>(x_in + ((size_t)c1 << 6) + (li << 2));
        uint2 u2 = *reinterpret_cast<const uint2*>(x_in + ((size_t)c2 << 6) + (li << 2));
        uint2 u3 = *reinterpret_cast<const uint2*>(x_in + ((size_t)c3 << 6) + (li << 2));
        uint2 u4 = *reinterpret_cast<const uint2*>(x_in + ((size_t)c4 << 6) + (li << 2));
        aA0 += v1 * blo(u1.x); aA1 += v1 * bhi(u1.x);
        aA2 += v1 * blo(u1.y); aA3 += v1 * bhi(u1.y);
        aB0 += v2 * blo(u2.x); aB1 += v2 * bhi(u2.x);
        aB2 += v2 * blo(u2.y); aB3 += v2 * bhi(u2.y);
        aC0 += v3 * blo(u3.x); aC1 += v3 * bhi(u3.x);
        aC2 += v3 * blo(u3.y); aC3 += v3 * bhi(u3.y);
        aD0 += v4 * blo(u4.x); aD1 += v4 * bhi(u4.x);
        aD2 += v4 * blo(u4.y); aD3 += v4 * bhi(u4.y);
    }
    for (; e0 < e_end; e0 += 4) {
        int e = e0 + g;
        if (e < e_end) {
            unsigned p = __builtin_nontemporal_load(ep + e);
            int   c = (int)(p >> 15);
            float v = (float)(p & 0x7fffu) * (1.f / 1048576.f);
            uint2 u = *reinterpret_cast<const uint2*>(x_in + ((size_t)c << 6) + (li << 2));
            aA0 += v * blo(u.x); aA1 += v * bhi(u.x);
            aA2 += v * blo(u.y); aA3 += v * bhi(u.y);
        }
    }
    float a0 = (aA0 + aB0) + (aC0 + aD0);
    float a1 = (aA1 + aB1) + (aC1 + aD1);
    float a2 = (aA2 + aB2) + (aC2 + aD2);
    float a3 = (aA3 + aB3) + (aC3 + aD3);
#pragma unroll
    for (int off = 16; off < 64; off <<= 1) {
        a0 += __shfl_xor(a0, off);
        a1 += __shfl_xor(a1, off);
        a2 += __shfl_xor(a2, off);
        a3 += __shfl_xor(a3, off);
    }
    if (g == 0) {
        size_t o = ((size_t)r << 6) + (li << 2);
        const unsigned* hp = reinterpret_cast<const unsigned*>(h + o);
        unsigned hx = __builtin_nontemporal_load(hp);
        unsigned hy = __builtin_nontemporal_load(hp + 1);
        float r0 = (1.f - ALPHA_C) * a0 + ALPHA_C * blo(hx);
        float r1 = (1.f - ALPHA_C) * a1 + ALPHA_C * bhi(hx);
        float r2 = (1.f - ALPHA_C) * a2 + ALPHA_C * blo(hy);
        float r3 = (1.f - ALPHA_C) * a3 + ALPHA_C * bhi(hy);
        uint2 ou;
        ou.x = ((unsigned)f2b(r1) << 16) | f2b(r0);
        ou.y = ((unsigned)f2b(r3) << 16) | f2b(r2);
        *reinterpret_cast<uint2*>(x_out + o) = ou;
    }
}

// ---------------- log_softmax (bf16 in, fp32 out) ----------------
__global__ __launch_bounds__(256) void lsm_kernel(
    const unsigned short* __restrict__ x, float* __restrict__ out, int n)
{
    const int wid = threadIdx.x >> 6, lane = threadIdx.x & 63;
    const int r = blockIdx.x * 4 + wid;
    if (r >= n) return;
    float v = b2f(x[(size_t)r * NCLS + lane]);
    float m = v;
#pragma unroll
    for (int o = 32; o > 0; o >>= 1) m = fmaxf(m, __shfl_xor(m, o));
    float ex = expf(v - m);
    float s = ex;
#pragma unroll
    for (int o = 32; o > 0; o >>= 1) s += __shfl_xor(s, o);
    out[(size_t)r * NCLS + lane] = (v - m) - logf(s);
}

extern "C" void kernel_launch(void* const* d_in, const int* in_sizes, int n_in,
                              void* d_out, int out_size, void* d_ws, size_t ws_size,
                              hipStream_t stream)
{
    const float* feat = (const float*)d_in[0];
    const float* W1   = (const float*)d_in[1];
    const float* b1   = (const float*)d_in[2];
    const float* W2   = (const float*)d_in[3];
    const float* b2   = (const float*)d_in[4];
    const float* vals = (const float*)d_in[5];
    const int*   erow = (const int*)d_in[6];
    const int*   ecol = (const int*)d_in[7];
    const int N = in_sizes[0] / NFEAT;
    const int E = in_sizes[5];
    float* out = (float*)d_out;
    const int CE = (E + NPB - 1) / NPB;
    const int NC = NBUCKET * NPB;

    size_t off = 0;
    auto alloc = [&](size_t bytes) -> void* {
        void* p = (char*)d_ws + off;
        off += (bytes + 255) & ~(size_t)255;
        return p;
    };
    unsigned short*     h        = (unsigned short*)alloc((size_t)N * NCLS * 2);
    unsigned short*     xA       = (unsigned short*)alloc((size_t)N * NCLS * 2);
    unsigned short*     xB       = (unsigned short*)alloc((size_t)N * NCLS * 2);
    int*                row_ptr  = (int*)alloc((size_t)(N + 1) * 4);
    int*                cnts     = (int*)alloc((size_t)NC * 4);
    int*                S        = (int*)alloc((size_t)(NC + 1) * 4);
    int*                partials = (int*)alloc(256 * 4);
    unsigned*           ep       = (unsigned*)alloc((size_t)E * 4);
    unsigned long long* stage    = (unsigned long long*)alloc((size_t)E * 8);
    unsigned short*     W1T      = (unsigned short*)alloc((size_t)NHID * NFEAT * 2);
    unsigned short*     W2T      = (unsigned short*)alloc((size_t)NCLS * NHID * 2);
    // optional fast-path buffer (102.4 MB) -- only used if ws is big enough
    size_t off_before_featb = off;
    unsigned short*     featb    = (unsigned short*)alloc((size_t)N * NFEAT * 2);
    const bool use_bf16_feat = (off <= ws_size);
    if (!use_bf16_feat) off = off_before_featb;

    // 0. weight transpose+convert (tiny)
    cvtT_kernel<<<(NFEAT * NHID + 255) / 256, 256, 0, stream>>>(W1, W1T, NFEAT, 8);
    cvtT_kernel<<<(NHID * NCLS + 255) / 256, 256, 0, stream>>>(W2, W2T, NHID, 6);

    // 1. MLP: bf16-feat fast path when ws permits
    if (use_bf16_feat) {
        const long n8 = (long)N * NFEAT / 8;
        cvtF_kernel<<<(int)((n8 + 255) / 256), 256, 0, stream>>>(feat, featb, n8);
        mlp_mfma_bf16_kernel<<<(N + 63) / 64, 256, 0, stream>>>(featb, W1T, b1, W2T, b2, h, N);
    } else {
        mlp_mfma_kernel<<<(N + 63) / 64, 256, 0, stream>>>(feat, W1T, b1, W2T, b2, h, N);
    }

    // 2. 2-level scatter -> CSR (round-8 proven)
    countP1_kernel<<<NPB, 256, 0, stream>>>(erow, cnts, E, CE);
    scanA_kernel<<<NC / 1024, 1024, 0, stream>>>(cnts, S, partials, NC);
    scanB_kernel<<<1, 256, 0, stream>>>(partials, S, 256, NC);
    scanC_kernel<<<NC / 1024, 1024, 0, stream>>>(S, partials, NC);
    scatterA_kernel<<<NPB, 256, 0, stream>>>(vals, erow, ecol, S, stage, E, CE);
    scatterB_kernel<<<NBUCKET, 256, 0, stream>>>(stage, S, ep, row_ptr, N, E);

    // 3. K=10 propagation, ping-pong (round-8 proven)
    const int gprop = (N + 3) / 4;
    const unsigned short* cur = h;
    for (int i = 0; i < 10; ++i) {
        unsigned short* dst = (i & 1) ? xB : xA;
        spmm_kernel<<<gprop, 256, 0, stream>>>(cur, h, dst, row_ptr, ep, N);
        cur = dst;
    }

    // 4. log_softmax
    lsm_kernel<<<gprop, 256, 0, stream>>>(cur, out, N);
}